// Round 1
// baseline (5749.369 us; speedup 1.0000x reference)
//
#include <hip/hip_runtime.h>
#include <math.h>

#define HIDDEN 1024
#define NBATCH 4
#define SEQ    4096
#define NKQ    4096

// ---------------------------------------------------------------------------
// NT GEMM: C[m,n] = scale * sum_k A[m,k]*B[n,k] (+ bias[n])
// A: [M,K] row-major (lda=K), B: [N,K] row-major (ldb=K), C: [M,N]
// Batched via blockIdx.z with strides sA/sB/sC.
// Tiles: BM=BN=64, BK=16, 256 threads, 4x4 microtile per thread.
// ---------------------------------------------------------------------------
template <bool HAS_BIAS>
__global__ __launch_bounds__(256) void gemm_nt_kernel(
    const float* __restrict__ A, const float* __restrict__ B,
    const float* __restrict__ bias, float* __restrict__ C,
    int M, int N, int K, long sA, long sB, long sC, float scale)
{
    constexpr int BM = 64, BN = 64, BK = 16;
    __shared__ float As[BK][BM + 4];  // +4 pad: keeps 16B alignment, breaks conflicts
    __shared__ float Bs[BK][BN + 4];

    const int tid = threadIdx.x;
    const int bm = blockIdx.y * BM;
    const int bn = blockIdx.x * BN;
    A += (long)blockIdx.z * sA;
    B += (long)blockIdx.z * sB;
    C += (long)blockIdx.z * sC;

    // loader mapping: each thread loads one float4 along k
    const int lr = tid >> 2;          // 0..63 : row within tile
    const int lk = (tid & 3) * 4;     // 0,4,8,12 : k offset
    // compute mapping
    const int tx = tid & 15;          // column group
    const int ty = tid >> 4;          // row group

    float acc[4][4] = {};

    for (int kt = 0; kt < K; kt += BK) {
        const float4 av = *(const float4*)&A[(long)(bm + lr) * K + kt + lk];
        const float4 bv = *(const float4*)&B[(long)(bn + lr) * K + kt + lk];
        __syncthreads();  // previous iteration's reads done before overwrite
        As[lk + 0][lr] = av.x; As[lk + 1][lr] = av.y;
        As[lk + 2][lr] = av.z; As[lk + 3][lr] = av.w;
        Bs[lk + 0][lr] = bv.x; Bs[lk + 1][lr] = bv.y;
        Bs[lk + 2][lr] = bv.z; Bs[lk + 3][lr] = bv.w;
        __syncthreads();
#pragma unroll
        for (int kk = 0; kk < BK; kk++) {
            const float4 a = *(const float4*)&As[kk][ty * 4];
            const float4 b = *(const float4*)&Bs[kk][tx * 4];
            const float ar[4] = {a.x, a.y, a.z, a.w};
            const float br[4] = {b.x, b.y, b.z, b.w};
#pragma unroll
            for (int i = 0; i < 4; i++)
#pragma unroll
                for (int j = 0; j < 4; j++)
                    acc[i][j] += ar[i] * br[j];
        }
    }

#pragma unroll
    for (int i = 0; i < 4; i++) {
        const int row = bm + ty * 4 + i;
        const int col = bn + tx * 4;
        float4 out;
        out.x = acc[i][0] * scale; out.y = acc[i][1] * scale;
        out.z = acc[i][2] * scale; out.w = acc[i][3] * scale;
        if (HAS_BIAS) {
            const float4 bb = *(const float4*)&bias[col];
            out.x += bb.x; out.y += bb.y; out.z += bb.z; out.w += bb.w;
        }
        *(float4*)&C[(long)row * N + col] = out;
    }
}

// ---------------------------------------------------------------------------
// TN GEMM: C[i,j] = sum_s A[s,i]*B[s,j]
// A: [K,M] row-major (lda), B: [K,N] row-major (ldb), C: [M,N]
// Used for context = attn^T @ v.  Loads need no transpose (coalesced in i/j).
// ---------------------------------------------------------------------------
__global__ __launch_bounds__(256) void gemm_tn_kernel(
    const float* __restrict__ A, const float* __restrict__ B,
    float* __restrict__ C, int M, int N, int K, int lda, int ldb,
    long sA, long sB, long sC)
{
    constexpr int BM = 64, BN = 64, BK = 16;
    __shared__ float As[BK][BM + 4];
    __shared__ float Bs[BK][BN + 4];

    const int tid = threadIdx.x;
    const int bm = blockIdx.y * BM;
    const int bn = blockIdx.x * BN;
    A += (long)blockIdx.z * sA;
    B += (long)blockIdx.z * sB;
    C += (long)blockIdx.z * sC;

    const int li  = (tid & 15) * 4;  // 0..60 : element offset within tile row
    const int lkk = tid >> 4;        // 0..15 : k row
    const int tx = tid & 15;
    const int ty = tid >> 4;

    float acc[4][4] = {};

    for (int kt = 0; kt < K; kt += BK) {
        const float4 av = *(const float4*)&A[(long)(kt + lkk) * lda + bm + li];
        const float4 bv = *(const float4*)&B[(long)(kt + lkk) * ldb + bn + li];
        __syncthreads();
        *(float4*)&As[lkk][li] = av;
        *(float4*)&Bs[lkk][li] = bv;
        __syncthreads();
#pragma unroll
        for (int kk = 0; kk < BK; kk++) {
            const float4 a = *(const float4*)&As[kk][ty * 4];
            const float4 b = *(const float4*)&Bs[kk][tx * 4];
            const float ar[4] = {a.x, a.y, a.z, a.w};
            const float br[4] = {b.x, b.y, b.z, b.w};
#pragma unroll
            for (int i = 0; i < 4; i++)
#pragma unroll
                for (int j = 0; j < 4; j++)
                    acc[i][j] += ar[i] * br[j];
        }
    }

#pragma unroll
    for (int i = 0; i < 4; i++) {
        const int row = bm + ty * 4 + i;
        const int col = bn + tx * 4;
        float4 out;
        out.x = acc[i][0]; out.y = acc[i][1]; out.z = acc[i][2]; out.w = acc[i][3];
        *(float4*)&C[(long)row * N + col] = out;
    }
}

// ---------------------------------------------------------------------------
// Column softmax over s for scores laid out [S, NKQ] per batch.
// One thread per kq column; lane-consecutive columns -> coalesced rows.
// Pass 1: online max+sum.  Pass 2: write normalized weights.
// ---------------------------------------------------------------------------
__global__ __launch_bounds__(256) void softmax_cols_kernel(float* __restrict__ att)
{
    const int c = blockIdx.x * 256 + threadIdx.x;       // kq column
    const long base = (long)blockIdx.y * SEQ * NKQ + c; // batch offset

    float m = -INFINITY, sum = 0.f;
    for (int s = 0; s < SEQ; s++) {
        const float x = att[base + (long)s * NKQ];
        const float mn = fmaxf(m, x);
        sum = sum * __expf(m - mn) + __expf(x - mn);
        m = mn;
    }
    const float inv = 1.0f / sum;
    for (int s = 0; s < SEQ; s++) {
        const long idx = base + (long)s * NKQ;
        att[idx] = __expf(att[idx] - m) * inv;
    }
}

// ---------------------------------------------------------------------------
extern "C" void kernel_launch(void* const* d_in, const int* in_sizes, int n_in,
                              void* d_out, int out_size, void* d_ws, size_t ws_size,
                              hipStream_t stream)
{
    const float* queries = (const float*)d_in[0];
    const float* keys    = (const float*)d_in[1];
    const float* values  = (const float*)d_in[2];
    const float* Wq = (const float*)d_in[3]; const float* bq = (const float*)d_in[4];
    const float* Wk = (const float*)d_in[5]; const float* bk = (const float*)d_in[6];
    const float* Wv = (const float*)d_in[7]; const float* bv = (const float*)d_in[8];

    float* ctx  = (float*)d_out;                          // [B, KQ, H]
    float* attn = ctx + (long)NBATCH * NKQ * HIDDEN;      // [B, S, KQ]

    float* q = (float*)d_ws;                              // [B, KQ, H]
    float* k = q + (long)NBATCH * NKQ * HIDDEN;           // [B, S, H]
    float* v = k + (long)NBATCH * SEQ * HIDDEN;           // [B, S, H]

    const dim3 blk(256);
    const float scaling = 0.03125f;  // rsqrt(1024)

    // ---- projections: X @ W^T + b, M = B*4096 flattened, K = N = 1024 ----
    gemm_nt_kernel<true><<<dim3(HIDDEN / 64, NBATCH * NKQ / 64, 1), blk, 0, stream>>>(
        queries, Wq, bq, q, NBATCH * NKQ, HIDDEN, HIDDEN, 0, 0, 0, 1.0f);
    gemm_nt_kernel<true><<<dim3(HIDDEN / 64, NBATCH * SEQ / 64, 1), blk, 0, stream>>>(
        keys, Wk, bk, k, NBATCH * SEQ, HIDDEN, HIDDEN, 0, 0, 0, 1.0f);
    gemm_nt_kernel<true><<<dim3(HIDDEN / 64, NBATCH * SEQ / 64, 1), blk, 0, stream>>>(
        values, Wv, bv, v, NBATCH * SEQ, HIDDEN, HIDDEN, 0, 0, 0, 1.0f);

    // ---- scores[b,s,kq] = k[b,s,:].q[b,kq,:] * scaling ----
    gemm_nt_kernel<false><<<dim3(NKQ / 64, SEQ / 64, NBATCH), blk, 0, stream>>>(
        k, q, nullptr, attn, SEQ, NKQ, HIDDEN,
        (long)SEQ * HIDDEN, (long)NKQ * HIDDEN, (long)SEQ * NKQ, scaling);

    // ---- softmax over s (axis 1) in place ----
    softmax_cols_kernel<<<dim3(NKQ / 256, NBATCH), blk, 0, stream>>>(attn);

    // ---- context[b,kq,h] = sum_s attn[b,s,kq] * v[b,s,h] ----
    gemm_tn_kernel<<<dim3(HIDDEN / 64, NKQ / 64, NBATCH), blk, 0, stream>>>(
        attn, v, ctx, NKQ, HIDDEN, SEQ, NKQ, HIDDEN,
        (long)SEQ * NKQ, (long)SEQ * HIDDEN, (long)NKQ * HIDDEN);
}

// Round 2
// 1440.767 us; speedup vs baseline: 3.9905x; 3.9905x over previous
//
#include <hip/hip_runtime.h>
#include <math.h>

#define HIDDEN 1024
#define NBATCH 4
#define SEQ    4096
#define NKQ    4096

typedef unsigned short us;
typedef __attribute__((ext_vector_type(8))) short short8;
typedef __attribute__((ext_vector_type(4))) float f32x4;

// round-to-nearest-even fp32 -> bf16 bits
__device__ __forceinline__ us f2b(float f) {
    unsigned u = __float_as_uint(f);
    return (us)((u + 0x7fffu + ((u >> 16) & 1u)) >> 16);
}

// async 16B global -> LDS (wave-uniform base + lane*16 layout required)
__device__ __forceinline__ void glds16(const void* g, void* l) {
    __builtin_amdgcn_global_load_lds(
        (const __attribute__((address_space(1))) unsigned*)g,
        (__attribute__((address_space(3))) unsigned*)l, 16, 0, 0);
}

// ---------------------------------------------------------------------------
// NT GEMM, bf16 MFMA 16x16x32: C[m,n] = scale * sum_k A[m,k]*B[n,k] (+bias[n])
// A: fp32 (convert-on-stage) or bf16 (global_load_lds). B: bf16 [N,K].
// 128x128 tile, BK=32, 256 threads = 4 waves, each wave a 64x64 subtile.
// ---------------------------------------------------------------------------
template <bool A_IS_F32, bool HAS_BIAS, bool OUT_BF16>
__global__ __launch_bounds__(256) void gemm_nt(
    const void* __restrict__ Av, const us* __restrict__ B,
    const float* __restrict__ bias, void* __restrict__ Cv,
    int M, int N, int K, long sA, long sB, long sC, float scale)
{
    __shared__ us As[128 * 32];   // 8 KB, row-major [row][k]
    __shared__ us Bs[128 * 32];   // 8 KB

    const int tid = threadIdx.x;
    const int bm = blockIdx.y * 128;
    const int bn = blockIdx.x * 128;
    const int lane = tid & 63;
    const int wv   = tid >> 6;
    const int wm = (wv >> 1) * 64;       // wave subtile origin
    const int wn = (wv & 1) * 64;
    const int fm = lane & 15;            // fragment row/col within 16
    const int q8 = (lane >> 4) * 8;      // fragment k offset

    // B staging: thread t loads 8 bf16 of row (bn + t>>2), chunk t&3; 2 issues
    const us* Bg = B + (long)blockIdx.z * sB + (long)(bn + (tid >> 2)) * K + (tid & 3) * 8;
    us* BsT = &Bs[tid * 8];

    // A staging pointers
    const us*    Agb = nullptr;
    const float* Agf = nullptr;
    us* AsTb = nullptr;
    us* AsTf = nullptr;
    if (A_IS_F32) {
        Agf  = (const float*)Av + (long)blockIdx.z * sA + (long)(bm + (tid >> 3)) * K + (tid & 7) * 4;
        AsTf = &As[(tid >> 3) * 32 + (tid & 7) * 4];
    } else {
        Agb  = (const us*)Av + (long)blockIdx.z * sA + (long)(bm + (tid >> 2)) * K + (tid & 3) * 8;
        AsTb = &As[tid * 8];
    }

    f32x4 acc[4][4];
#pragma unroll
    for (int i = 0; i < 4; i++)
#pragma unroll
        for (int j = 0; j < 4; j++)
            acc[i][j] = (f32x4){0.f, 0.f, 0.f, 0.f};

    for (int kt = 0; kt < K; kt += 32) {
        float4 fa[4];
        if (A_IS_F32) {
#pragma unroll
            for (int e = 0; e < 4; e++)
                fa[e] = *(const float4*)(Agf + (long)(32 * e) * K + kt);
        }
        __syncthreads();  // previous iteration's frag reads complete
        // B tile via async DMA
        glds16(Bg + kt, BsT);
        glds16(Bg + kt + (long)64 * K, BsT + 2048);
        if (A_IS_F32) {
#pragma unroll
            for (int e = 0; e < 4; e++) {
                ushort4 h;
                h.x = f2b(fa[e].x); h.y = f2b(fa[e].y);
                h.z = f2b(fa[e].z); h.w = f2b(fa[e].w);
                *(ushort4*)(AsTf + 1024 * e) = h;
            }
        } else {
            glds16(Agb + kt, AsTb);
            glds16(Agb + kt + (long)64 * K, AsTb + 2048);
        }
        __syncthreads();  // staging complete

        short8 af[4], bf[4];
#pragma unroll
        for (int mi = 0; mi < 4; mi++)
            af[mi] = *(const short8*)&As[(wm + mi * 16 + fm) * 32 + q8];
#pragma unroll
        for (int ni = 0; ni < 4; ni++)
            bf[ni] = *(const short8*)&Bs[(wn + ni * 16 + fm) * 32 + q8];
#pragma unroll
        for (int mi = 0; mi < 4; mi++)
#pragma unroll
            for (int ni = 0; ni < 4; ni++)
                acc[mi][ni] = __builtin_amdgcn_mfma_f32_16x16x32_bf16(
                    af[mi], bf[ni], acc[mi][ni], 0, 0, 0);
    }

    // epilogue: C/D layout col=lane&15, row=(lane>>4)*4+reg
    const int er4 = (lane >> 4) * 4;
#pragma unroll
    for (int ni = 0; ni < 4; ni++) {
        const int col = bn + wn + ni * 16 + fm;
        const float bv = HAS_BIAS ? bias[col] : 0.0f;
#pragma unroll
        for (int mi = 0; mi < 4; mi++) {
#pragma unroll
            for (int r = 0; r < 4; r++) {
                const int row = bm + wm + mi * 16 + er4 + r;
                const float v = acc[mi][ni][r] * scale + bv;
                const long idx = (long)blockIdx.z * sC + (long)row * N + col;
                if (OUT_BF16) ((us*)Cv)[idx] = f2b(v);
                else          ((float*)Cv)[idx] = v;
            }
        }
    }
}

// ---------------------------------------------------------------------------
// fp32 -> bf16 elementwise (weights)
// ---------------------------------------------------------------------------
__global__ __launch_bounds__(256) void f2b_kernel(const float* __restrict__ in,
                                                  us* __restrict__ out, int n)
{
    const int i = (blockIdx.x * 256 + threadIdx.x) * 4;
    if (i < n) {
        const float4 f = *(const float4*)&in[i];
        ushort4 h;
        h.x = f2b(f.x); h.y = f2b(f.y); h.z = f2b(f.z); h.w = f2b(f.w);
        *(ushort4*)&out[i] = h;
    }
}

// ---------------------------------------------------------------------------
// bf16 transpose: in [SEQ][HIDDEN] -> out [HIDDEN][SEQ], per batch (z)
// ---------------------------------------------------------------------------
__global__ __launch_bounds__(256) void transpose_b_kernel(const us* __restrict__ in,
                                                          us* __restrict__ out)
{
    __shared__ us tile[64][72];
    const int t = threadIdx.x;
    const long ib = (long)blockIdx.z * SEQ * HIDDEN;
    const long ob = (long)blockIdx.z * (long)HIDDEN * SEQ;
    const int s0 = blockIdx.y * 64, h0 = blockIdx.x * 64;
    const int r = t >> 3, c = (t & 7) * 8;
#pragma unroll
    for (int e = 0; e < 2; e++) {
        const int rr = r + 32 * e;
        const uint4 v = *(const uint4*)&in[ib + (long)(s0 + rr) * HIDDEN + h0 + c];
        us* dst = &tile[rr][c];
        ((uint*)dst)[0] = v.x; ((uint*)dst)[1] = v.y;
        ((uint*)dst)[2] = v.z; ((uint*)dst)[3] = v.w;
    }
    __syncthreads();
#pragma unroll
    for (int e = 0; e < 2; e++) {
        const int rr = r + 32 * e;   // h index within tile
        us vals[8];
#pragma unroll
        for (int j = 0; j < 8; j++) vals[j] = tile[c + j][rr];
        *(uint4*)&out[ob + (long)(h0 + rr) * SEQ + s0 + c] = *(uint4*)vals;
    }
}

// ---------------------------------------------------------------------------
// row softmax in place: a is [rows][SEQ] fp32, one block per row
// ---------------------------------------------------------------------------
__global__ __launch_bounds__(256) void softmax_rows_kernel(float* __restrict__ a)
{
    float* row = a + ((long)blockIdx.y * NKQ + blockIdx.x) * SEQ;
    const int t = threadIdx.x;
    const int lane = t & 63, wv = t >> 6;
    __shared__ float red[8];

    float4 x[4];
    float m = -INFINITY;
#pragma unroll
    for (int e = 0; e < 4; e++) {
        x[e] = *(const float4*)&row[t * 4 + 1024 * e];
        m = fmaxf(m, fmaxf(fmaxf(x[e].x, x[e].y), fmaxf(x[e].z, x[e].w)));
    }
#pragma unroll
    for (int o = 32; o; o >>= 1) m = fmaxf(m, __shfl_xor(m, o));
    if (lane == 0) red[wv] = m;
    __syncthreads();
    m = fmaxf(fmaxf(red[0], red[1]), fmaxf(red[2], red[3]));

    float s = 0.f;
#pragma unroll
    for (int e = 0; e < 4; e++) {
        x[e].x = __expf(x[e].x - m); x[e].y = __expf(x[e].y - m);
        x[e].z = __expf(x[e].z - m); x[e].w = __expf(x[e].w - m);
        s += x[e].x + x[e].y + x[e].z + x[e].w;
    }
#pragma unroll
    for (int o = 32; o; o >>= 1) s += __shfl_xor(s, o);
    if (lane == 0) red[4 + wv] = s;
    __syncthreads();
    s = red[4] + red[5] + red[6] + red[7];

    const float inv = 1.0f / s;
#pragma unroll
    for (int e = 0; e < 4; e++) {
        x[e].x *= inv; x[e].y *= inv; x[e].z *= inv; x[e].w *= inv;
        *(float4*)&row[t * 4 + 1024 * e] = x[e];
    }
}

// ---------------------------------------------------------------------------
// in-place fp32 square transpose (4096x4096 per batch) via 64x64 tile pairs
// ---------------------------------------------------------------------------
__global__ __launch_bounds__(256) void transpose_f32_ip_kernel(float* __restrict__ a)
{
    const int ti = blockIdx.y, tj = blockIdx.x;
    if (tj < ti) return;
    float* base = a + (long)blockIdx.z * NKQ * SEQ;
    __shared__ float ta[64][65];
    __shared__ float tb[64][65];
    const int t = threadIdx.x, r = t >> 4, c = (t & 15) * 4;
    const bool diag = (ti == tj);
#pragma unroll
    for (int e = 0; e < 4; e++) {
        const int rr = r + 16 * e;
        const float4 va = *(const float4*)&base[(long)(ti * 64 + rr) * 4096 + tj * 64 + c];
        ta[rr][c] = va.x; ta[rr][c + 1] = va.y; ta[rr][c + 2] = va.z; ta[rr][c + 3] = va.w;
        if (!diag) {
            const float4 vb = *(const float4*)&base[(long)(tj * 64 + rr) * 4096 + ti * 64 + c];
            tb[rr][c] = vb.x; tb[rr][c + 1] = vb.y; tb[rr][c + 2] = vb.z; tb[rr][c + 3] = vb.w;
        }
    }
    __syncthreads();
#pragma unroll
    for (int e = 0; e < 4; e++) {
        const int rr = r + 16 * e;
        float4 w;
        w.x = ta[c][rr]; w.y = ta[c + 1][rr]; w.z = ta[c + 2][rr]; w.w = ta[c + 3][rr];
        *(float4*)&base[(long)(tj * 64 + rr) * 4096 + ti * 64 + c] = w;
        if (!diag) {
            float4 u;
            u.x = tb[c][rr]; u.y = tb[c + 1][rr]; u.z = tb[c + 2][rr]; u.w = tb[c + 3][rr];
            *(float4*)&base[(long)(ti * 64 + rr) * 4096 + tj * 64 + c] = u;
        }
    }
}

// ---------------------------------------------------------------------------
extern "C" void kernel_launch(void* const* d_in, const int* in_sizes, int n_in,
                              void* d_out, int out_size, void* d_ws, size_t ws_size,
                              hipStream_t stream)
{
    const float* queries = (const float*)d_in[0];
    const float* keys    = (const float*)d_in[1];
    const float* values  = (const float*)d_in[2];
    const float* Wq = (const float*)d_in[3]; const float* bq = (const float*)d_in[4];
    const float* Wk = (const float*)d_in[5]; const float* bk = (const float*)d_in[6];
    const float* Wv = (const float*)d_in[7]; const float* bv = (const float*)d_in[8];

    float* ctx  = (float*)d_out;                       // [B][KQ][H]
    float* attn = ctx + (long)NBATCH * NKQ * HIDDEN;   // [B][KQ][S] then transposed in place

    char* ws = (char*)d_ws;
    us* q_b  = (us*)(ws);                                  // [B][KQ][H] bf16, 32MB
    us* k_b  = (us*)(ws + (size_t)32 * 1024 * 1024);       // [B][S][H]
    us* v_b  = (us*)(ws + (size_t)64 * 1024 * 1024);       // [B][S][H]
    us* vT_b = (us*)(ws + (size_t)96 * 1024 * 1024);       // [B][H][S]
    us* Wqb  = (us*)(ws + (size_t)128 * 1024 * 1024);      // 2MB each
    us* Wkb  = Wqb + (size_t)HIDDEN * HIDDEN;
    us* Wvb  = Wkb + (size_t)HIDDEN * HIDDEN;

    const dim3 blk(256);
    const int nW = HIDDEN * HIDDEN;

    // weights -> bf16
    f2b_kernel<<<dim3(nW / 1024), blk, 0, stream>>>(Wq, Wqb, nW);
    f2b_kernel<<<dim3(nW / 1024), blk, 0, stream>>>(Wk, Wkb, nW);
    f2b_kernel<<<dim3(nW / 1024), blk, 0, stream>>>(Wv, Wvb, nW);

    // projections: [16384 x 1024] = fp32 in @ bf16 W^T + bias -> bf16
    gemm_nt<true, true, true><<<dim3(HIDDEN / 128, (NBATCH * NKQ) / 128, 1), blk, 0, stream>>>(
        queries, Wqb, bq, q_b, NBATCH * NKQ, HIDDEN, HIDDEN, 0, 0, 0, 1.0f);
    gemm_nt<true, true, true><<<dim3(HIDDEN / 128, (NBATCH * SEQ) / 128, 1), blk, 0, stream>>>(
        keys, Wkb, bk, k_b, NBATCH * SEQ, HIDDEN, HIDDEN, 0, 0, 0, 1.0f);
    gemm_nt<true, true, true><<<dim3(HIDDEN / 128, (NBATCH * SEQ) / 128, 1), blk, 0, stream>>>(
        values, Wvb, bv, v_b, NBATCH * SEQ, HIDDEN, HIDDEN, 0, 0, 0, 1.0f);

    // v_b [S][H] -> vT_b [H][S]
    transpose_b_kernel<<<dim3(HIDDEN / 64, SEQ / 64, NBATCH), blk, 0, stream>>>(v_b, vT_b);

    // scoresT[b][kq][s] = (1/32) * q_b[kq,:] . k_b[s,:]   -> attn region (fp32)
    gemm_nt<false, false, false><<<dim3(SEQ / 128, NKQ / 128, NBATCH), blk, 0, stream>>>(
        q_b, k_b, nullptr, attn, NKQ, SEQ, HIDDEN,
        (long)NKQ * HIDDEN, (long)SEQ * HIDDEN, (long)NKQ * SEQ, 0.03125f);

    // softmax over s (contiguous rows)
    softmax_rows_kernel<<<dim3(NKQ, NBATCH), blk, 0, stream>>>(attn);

    // context[b][kq][h] = sum_s attnT[kq,s] * vT_b[h,s]
    gemm_nt<true, false, false><<<dim3(HIDDEN / 128, NKQ / 128, NBATCH), blk, 0, stream>>>(
        attn, vT_b, nullptr, ctx, NKQ, HIDDEN, SEQ,
        (long)NKQ * SEQ, (long)HIDDEN * SEQ, (long)NKQ * HIDDEN, 1.0f);

    // attn [B][KQ][S] -> [B][S][KQ] in place
    transpose_f32_ip_kernel<<<dim3(64, 64, NBATCH), blk, 0, stream>>>(attn);
}